// Round 1
// baseline (1983.782 us; speedup 1.0000x reference)
//
#include <hip/hip_runtime.h>
#include <cstdint>
#include <cstddef>

// Problem constants
#define B_    2048
#define H_    256
#define S_    64
#define NSTEP 32
#define OUTS  33
#define N4H   1024            // 4*H gate cols, permuted n = j*4 + g
#define XROWSTRIDE (S_ * H_)  // x0 batch-row stride (fixed t)
#define EPI_STRIDE 1028       // floats; %32==4 -> 2-way (free) on C-layout writes

typedef _Float16 f16;
typedef _Float16 f16x4 __attribute__((ext_vector_type(4)));
typedef _Float16 f16x8 __attribute__((ext_vector_type(8)));
typedef float    f32x4 __attribute__((ext_vector_type(4)));

__device__ __forceinline__ float sigm(float x)  { return 1.f / (1.f + __expf(-x)); }
__device__ __forceinline__ float tanh_(float x) { return 1.f - 2.f / (1.f + __expf(2.f * x)); }

// ---------------------------------------------------------------------------
// Prep: quantize + pack weights into MFMA-B-fragment-major f16 layout:
//   dest[((ct*KT + kk)*64 + q*16 + c15)*8 + e] = W[n = ct*16+c15][k = kk*32+q*8+e]
// so a lane's fragment is one contiguous 16B load.
//   WeP: encoder, KT=16, k in [0,512) = [W_ih | W_hh], n permuted j*4+g
//   WaP: AR, KT=8, W_ih + W_hh pre-summed (x == h in AR phase)
//   pb : permuted bias sum
// ---------------------------------------------------------------------------
__global__ __launch_bounds__(256) void prep_kernel(
    const float* __restrict__ W_ih, const float* __restrict__ W_hh,
    const float* __restrict__ b_ih, const float* __restrict__ b_hh,
    f16* __restrict__ WeP, f16* __restrict__ WaP, float* __restrict__ pb)
{
    int t = blockIdx.x * 256 + threadIdx.x;
    if (t < N4H * 64) {                 // encoder pack: 8 elems/thread
        int n  = t >> 6;                // permuted col 0..1023
        int kc = (t & 63) * 8;          // k base 0..504
        int j = n >> 2, g = n & 3;
        const float* src = (kc < H_) ? &W_ih[(size_t)(g * H_ + j) * H_ + kc]
                                     : &W_hh[(size_t)(g * H_ + j) * H_ + kc - H_];
        f16x8 v;
#pragma unroll
        for (int e = 0; e < 8; ++e) v[e] = (f16)src[e];
        int ct = n >> 4, c15 = n & 15, kk = kc >> 5, q = (kc >> 3) & 3;
        *(f16x8*)&WeP[((size_t)(ct * 16 + kk) * 64 + q * 16 + c15) * 8] = v;
    } else if (t < N4H * 64 + N4H * 32) {   // AR pack (Wsum), KT=8
        int u  = t - N4H * 64;
        int n  = u >> 5;
        int kc = (u & 31) * 8;
        int j = n >> 2, g = n & 3;
        const float* s1 = &W_ih[(size_t)(g * H_ + j) * H_ + kc];
        const float* s2 = &W_hh[(size_t)(g * H_ + j) * H_ + kc];
        f16x8 v;
#pragma unroll
        for (int e = 0; e < 8; ++e) v[e] = (f16)(s1[e] + s2[e]);
        int ct = n >> 4, c15 = n & 15, kk = kc >> 5, q = (kc >> 3) & 3;
        *(f16x8*)&WaP[((size_t)(ct * 8 + kk) * 64 + q * 16 + c15) * 8] = v;
    } else if (t < N4H * 64 + N4H * 32 + N4H) {
        int n = t - (N4H * 64 + N4H * 32);
        int j = n >> 2, g = n & 3;
        pb[n] = b_ih[g * H_ + j] + b_hh[g * H_ + j];
    }
}

// ---------------------------------------------------------------------------
// Fully fused LSTM: ONE kernel runs all 64 encoder + 32 AR steps.
//   128 blocks x 1024 threads (16 waves). Block owns 16 batch rows and ALL
//   1024 gate cols -> every step dependency is block-local (__syncthreads only,
//   no grid sync, no cross-XCD coherence needed).
//   - Encoder B fragments: 256 VGPRs/lane, persistent across all 64 steps.
//     AR fragments (128 VGPRs) overwrite them once. Weights never re-read.
//   - h lives in LDS (written by the cell directly in A-fragment layout),
//     c lives in 4 VGPRs/thread. No h/c global traffic, no memsets.
//   - x_{t+1} prefetched into regs under step t's MFMA phase.
//   - 2 barriers per step.
// Cell thread map: wave w = row w, lane l handles j = l + 64*i (i=0..3):
//   sEpi reads are lane-contiguous f32x4 (conflict-free), out stores coalesced.
// ---------------------------------------------------------------------------
__global__ __launch_bounds__(1024, 1) void lstm_fused(
    const float* __restrict__ x0,
    const f16*  __restrict__ WeP,
    const f16*  __restrict__ WaP,
    const float* __restrict__ pb,
    float* __restrict__ out)
{
    // sA: A operand, fragment-major. kk 0..7 = x half (encoder), kk 8..15 = h.
    __shared__ __align__(16) f16   sA[16 * 64 * 8];          // 16 KB
    __shared__ __align__(16) float sEpi[16 * EPI_STRIDE];    // 65.8 KB

    const int tid = threadIdx.x;
    const int l   = tid & 63;
    const int w   = tid >> 6;            // wave id == cell row
    const int b0  = blockIdx.x * 16;

    f16* hA = &sA[8 * 64 * 8];           // h region (AR reads kk 0..7 from here)

    // ---- persistent encoder weights: global(L2) -> VGPR, one-time ----
    f16x8 Bf[4][16];
#pragma unroll
    for (int f = 0; f < 4; ++f) {
        const int ct = w * 4 + f;        // wave w owns cols [w*64, w*64+64)
#pragma unroll
        for (int kk = 0; kk < 16; ++kk)
            Bf[f][kk] = *(const f16x8*)&WeP[((size_t)(ct * 16 + kk) * 64 + l) * 8];
    }

    // ---- bias in regs (fixed thread->gate map for all 96 steps) ----
    f32x4 pbr[4];
#pragma unroll
    for (int i = 0; i < 4; ++i)
        pbr[i] = *(const f32x4*)&pb[4 * l + 256 * i];

    // ---- c state in regs: c[row=w][j = l + 64*i] ----
    float cs[4] = {0.f, 0.f, 0.f, 0.f};

    // ---- h0 = 0; stage x_0 ----
    if (tid < 512) {
        f16x8 z;
#pragma unroll
        for (int e = 0; e < 8; ++e) z[e] = (f16)0.f;
        ((f16x8*)hA)[tid] = z;
    }
    {
        const int kc = (tid & 63) * 4;   // row = w
        float4 v = *(const float4*)&x0[(size_t)(b0 + w) * XROWSTRIDE + kc];
        f16x4 x4;
        x4[0] = (f16)v.x; x4[1] = (f16)v.y; x4[2] = (f16)v.z; x4[3] = (f16)v.w;
        *(f16x4*)&sA[((kc >> 5) * 64 + ((kc >> 3) & 3) * 16 + w) * 8 + (kc & 7)] = x4;
    }
    __syncthreads();

    const int q = l >> 4, c15 = l & 15;

    // ================= encoder: 64 steps, K = 512 =================
    for (int t = 0; t < S_; ++t) {
        // prefetch x_{t+1} (latency hidden under MFMA phase)
        float4 xv;
        const int kc = (tid & 63) * 4;
        if (t + 1 < S_)
            xv = *(const float4*)&x0[(size_t)(b0 + w) * XROWSTRIDE + (t + 1) * H_ + kc];

        f32x4 acc[4];
#pragma unroll
        for (int f = 0; f < 4; ++f) acc[f] = (f32x4){0.f, 0.f, 0.f, 0.f};
#pragma unroll
        for (int kk = 0; kk < 16; ++kk) {
            f16x8 a = *(const f16x8*)&sA[(kk * 64 + l) * 8];
#pragma unroll
            for (int f = 0; f < 4; ++f)
                acc[f] = __builtin_amdgcn_mfma_f32_16x16x32_f16(a, Bf[f][kk], acc[f], 0, 0, 0);
        }
        // C layout: col = c15 (lane), row = q*4 + r
#pragma unroll
        for (int f = 0; f < 4; ++f)
#pragma unroll
            for (int r = 0; r < 4; ++r)
                sEpi[(q * 4 + r) * EPI_STRIDE + w * 64 + f * 16 + c15] = acc[f][r];
        __syncthreads();

        // fused cell (all 16 waves; wave w handles row w)
        float hv[4];
#pragma unroll
        for (int i = 0; i < 4; ++i) {
            f32x4 g4 = *(const f32x4*)&sEpi[w * EPI_STRIDE + 4 * l + 256 * i];
            float vi = g4[0] + pbr[i][0];
            float vf = g4[1] + pbr[i][1];
            float vg = g4[2] + pbr[i][2];
            float vo = g4[3] + pbr[i][3];
            float ig = sigm(vi), fg = sigm(vf), gg = tanh_(vg), og = sigm(vo);
            float cn = fg * cs[i] + ig * gg;
            float hn = og * tanh_(cn);
            cs[i] = cn; hv[i] = hn;
            const int j = l + 64 * i;    // h -> A-fragment layout, f16 scatter
            hA[((j >> 5) * 64 + ((j >> 3) & 3) * 16 + w) * 8 + (j & 7)] = (f16)hn;
        }
        if (t == S_ - 1) {
#pragma unroll
            for (int i = 0; i < 4; ++i)
                out[(size_t)(b0 + w) * (OUTS * H_) + l + 64 * i] = hv[i];
        }
        if (t + 1 < S_) {
            f16x4 x4;
            x4[0] = (f16)xv.x; x4[1] = (f16)xv.y; x4[2] = (f16)xv.z; x4[3] = (f16)xv.w;
            *(f16x4*)&sA[((kc >> 5) * 64 + ((kc >> 3) & 3) * 16 + w) * 8 + (kc & 7)] = x4;
        }
        __syncthreads();
    }

    // ---- swap in AR weights (pre-summed W_ih+W_hh), K = 256 ----
#pragma unroll
    for (int f = 0; f < 4; ++f) {
        const int ct = w * 4 + f;
#pragma unroll
        for (int kk = 0; kk < 8; ++kk)
            Bf[f][kk] = *(const f16x8*)&WaP[((size_t)(ct * 8 + kk) * 64 + l) * 8];
    }

    // ================= AR rollout: 32 steps, A = h =================
    for (int t = 0; t < NSTEP; ++t) {
        f32x4 acc[4];
#pragma unroll
        for (int f = 0; f < 4; ++f) acc[f] = (f32x4){0.f, 0.f, 0.f, 0.f};
#pragma unroll
        for (int kk = 0; kk < 8; ++kk) {
            f16x8 a = *(const f16x8*)&hA[(kk * 64 + l) * 8];
#pragma unroll
            for (int f = 0; f < 4; ++f)
                acc[f] = __builtin_amdgcn_mfma_f32_16x16x32_f16(a, Bf[f][kk], acc[f], 0, 0, 0);
        }
#pragma unroll
        for (int f = 0; f < 4; ++f)
#pragma unroll
            for (int r = 0; r < 4; ++r)
                sEpi[(q * 4 + r) * EPI_STRIDE + w * 64 + f * 16 + c15] = acc[f][r];
        __syncthreads();

#pragma unroll
        for (int i = 0; i < 4; ++i) {
            f32x4 g4 = *(const f32x4*)&sEpi[w * EPI_STRIDE + 4 * l + 256 * i];
            float vi = g4[0] + pbr[i][0];
            float vf = g4[1] + pbr[i][1];
            float vg = g4[2] + pbr[i][2];
            float vo = g4[3] + pbr[i][3];
            float ig = sigm(vi), fg = sigm(vf), gg = tanh_(vg), og = sigm(vo);
            float cn = fg * cs[i] + ig * gg;
            float hn = og * tanh_(cn);
            cs[i] = cn;
            const int j = l + 64 * i;
            hA[((j >> 5) * 64 + ((j >> 3) & 3) * 16 + w) * 8 + (j & 7)] = (f16)hn;
            out[(size_t)(b0 + w) * (OUTS * H_) + (t + 1) * H_ + j] = hn;
        }
        __syncthreads();
    }
}

// ---------------------------------------------------------------------------
extern "C" void kernel_launch(void* const* d_in, const int* in_sizes, int n_in,
                              void* d_out, int out_size, void* d_ws, size_t ws_size,
                              hipStream_t stream) {
    const float* x0   = (const float*)d_in[0];
    const float* W_ih = (const float*)d_in[1];
    const float* W_hh = (const float*)d_in[2];
    const float* b_ih = (const float*)d_in[3];
    const float* b_hh = (const float*)d_in[4];
    float* out = (float*)d_out;

    // workspace (~1.6 MB): packed weights + bias only (h/c never touch global)
    char* p = (char*)d_ws;
    f16* WeP = (f16*)p; p += (size_t)N4H * 512 * 2;
    f16* WaP = (f16*)p; p += (size_t)N4H * 256 * 2;
    float* pb = (float*)p; p += (size_t)N4H * 4;

    const int prep_total = N4H * 64 + N4H * 32 + N4H;
    prep_kernel<<<dim3((prep_total + 255) / 256), dim3(256), 0, stream>>>(
        W_ih, W_hh, b_ih, b_hh, WeP, WaP, pb);

    // one persistent kernel: 128 blocks (16 rows each), 1024 threads, 1 block/CU
    lstm_fused<<<dim3(B_ / 16), dim3(1024), 0, stream>>>(x0, WeP, WaP, pb, out);
}

// Round 3
// 1095.778 us; speedup vs baseline: 1.8104x; 1.8104x over previous
//
#include <hip/hip_runtime.h>
#include <cstdint>
#include <cstddef>

// Problem constants
#define B_    2048
#define H_    256
#define S_    64
#define NSTEP 32
#define OUTS  33
#define N4H   1024            // 4*H gate cols, permuted n = j*4 + g
#define XROWSTRIDE (S_ * H_)  // x0 batch-row stride (fixed t)
#define EPI_STRIDE 260        // floats
#define NBLK  256
#define CNT_STRIDE 16         // u32s per group counter (64B line separation)

typedef _Float16 f16;
typedef _Float16 f16x8 __attribute__((ext_vector_type(8)));
typedef float    f32x4 __attribute__((ext_vector_type(4)));

__device__ __forceinline__ float sigm(float x)  { return 1.f / (1.f + __expf(-x)); }
__device__ __forceinline__ float tanh_(float x) { return 1.f - 2.f / (1.f + __expf(2.f * x)); }

// Swizzled sA offset (f16 units). t16 = fragment-row, slot 0..63.
// XOR breaks the 8-way bank conflict on staging writes; reads apply the same
// XOR so lane l still gets logical slot l (write s->s^x, read l->l^x).
__device__ __forceinline__ int sa_off(int t16, int slot) {
    return (t16 * 64 + (slot ^ (t16 & 7))) * 8;
}

// ---------------------------------------------------------------------------
// Group barrier: the 4 blocks sharing an M-tile sync via one L3 atomic
// counter. tid0 does release-fence -> arrive -> spin -> acquire-fence;
// __syncthreads brackets make it block-wide. Bounded spin: if co-residency
// ever failed we produce wrong results (visible) instead of a hang.
// ---------------------------------------------------------------------------
__device__ __forceinline__ void gsync(unsigned* cnt, unsigned target) {
    __syncthreads();                     // all stores of all waves complete
    if (threadIdx.x == 0) {
        __builtin_amdgcn_fence(__ATOMIC_RELEASE, "agent");   // wb L2 (dirty h/out)
        __hip_atomic_fetch_add(cnt, 1u, __ATOMIC_RELAXED, __HIP_MEMORY_SCOPE_AGENT);
        unsigned spins = 0;
        while (__hip_atomic_load(cnt, __ATOMIC_RELAXED, __HIP_MEMORY_SCOPE_AGENT) < target) {
            __builtin_amdgcn_s_sleep(2);
            if (++spins > (1u << 17)) break;   // fail-safe, never deadlock
        }
        __builtin_amdgcn_fence(__ATOMIC_ACQUIRE, "agent");   // inv L1/L2 (stale h)
    }
    __syncthreads();
}

// ---------------------------------------------------------------------------
// Prep: quantize + pack weights into MFMA-B-fragment-major f16 layout:
//   dest[((ct*KT + kk)*64 + q*16 + c15)*8 + e] = W[n = ct*16+c15][k = kk*32+q*8+e]
//   WeP: encoder, KT=16, k in [0,512) = [W_ih | W_hh], n permuted j*4+g
//   WaP: AR, KT=8, W_ih + W_hh pre-summed (x == h in AR phase)
//   pb : permuted bias sum
// ---------------------------------------------------------------------------
__global__ __launch_bounds__(256) void prep_kernel(
    const float* __restrict__ W_ih, const float* __restrict__ W_hh,
    const float* __restrict__ b_ih, const float* __restrict__ b_hh,
    f16* __restrict__ WeP, f16* __restrict__ WaP, float* __restrict__ pb)
{
    int t = blockIdx.x * 256 + threadIdx.x;
    if (t < N4H * 64) {                 // encoder pack: 8 elems/thread
        int n  = t >> 6;                // permuted col 0..1023
        int kc = (t & 63) * 8;          // k base 0..504
        int j = n >> 2, g = n & 3;
        const float* src = (kc < H_) ? &W_ih[(size_t)(g * H_ + j) * H_ + kc]
                                     : &W_hh[(size_t)(g * H_ + j) * H_ + kc - H_];
        f16x8 v;
#pragma unroll
        for (int e = 0; e < 8; ++e) v[e] = (f16)src[e];
        int ct = n >> 4, c15 = n & 15, kk = kc >> 5, q = (kc >> 3) & 3;
        *(f16x8*)&WeP[((size_t)(ct * 16 + kk) * 64 + q * 16 + c15) * 8] = v;
    } else if (t < N4H * 64 + N4H * 32) {   // AR pack (Wsum), KT=8
        int u  = t - N4H * 64;
        int n  = u >> 5;
        int kc = (u & 31) * 8;
        int j = n >> 2, g = n & 3;
        const float* s1 = &W_ih[(size_t)(g * H_ + j) * H_ + kc];
        const float* s2 = &W_hh[(size_t)(g * H_ + j) * H_ + kc];
        f16x8 v;
#pragma unroll
        for (int e = 0; e < 8; ++e) v[e] = (f16)(s1[e] + s2[e]);
        int ct = n >> 4, c15 = n & 15, kk = kc >> 5, q = (kc >> 3) & 3;
        *(f16x8*)&WaP[((size_t)(ct * 8 + kk) * 64 + q * 16 + c15) * 8] = v;
    } else if (t < N4H * 64 + N4H * 32 + N4H) {
        int n = t - (N4H * 64 + N4H * 32);
        int j = n >> 2, g = n & 3;
        pb[n] = b_ih[g * H_ + j] + b_hh[g * H_ + j];
    }
}

// ---------------------------------------------------------------------------
// Persistent LSTM, PLAIN launch (no cooperative API): one kernel, 96 steps.
//   Grid: 256 blocks x 256 threads (4 waves = 1 wave/SIMD -> 512 VGPR budget;
//   1 block/CU on 256 CUs -> all blocks co-resident by construction).
//   Block (m,n): rows m*32..+32, gate cols n*256..+256. Wave owns 64 cols.
//   Cross-block dependency is only within the 4-block group sharing m:
//   block (m,n) reads h rows of m written by (m,0..3). -> 4-block gsync.
//   - Encoder B fragments Bf[4][16] = 256 VGPRs/lane, persistent all 64 steps.
//     AR fragments (128 VGPRs) overwrite once. Weights never re-read.
//   - c in 8 VGPRs/thread. h ping-pongs via two global f16 buffers (16 KB per
//     group per step, L2/L3-resident).
//   - x_{t+1} prefetched into regs under the epilogue (completes before the
//     fence's vmcnt drain).
//   - bid swizzle: group members at bids {x, x+8, x+16, x+24} -> same XCD
//     under round-robin mapping -> h exchange is L2-local (perf only;
//     correctness comes from the agent fences).
// ---------------------------------------------------------------------------
__global__ __launch_bounds__(256, 1) void lstm_fused(
    const float* __restrict__ x0,
    const f16*  __restrict__ WeP,
    const f16*  __restrict__ WaP,
    const float* __restrict__ pb,
    f16* __restrict__ hb0, f16* __restrict__ hb1,
    unsigned* __restrict__ cnts,
    float* __restrict__ out)
{
    __shared__ __align__(16) unsigned char smem[32 * EPI_STRIDE * 4]; // 33.3 KB
    f16*   sA   = (f16*)smem;    // staged A tile (32 rows x K), frag-major
    float* sEpi = (float*)smem;  // gate tile 32 x 256 (overlaid, barrier-separated)

    const int tid = threadIdx.x;
    const int l   = tid & 63;
    const int w   = tid >> 6;                 // wave 0..3
    const int bid = blockIdx.x;
    const int n   = (bid >> 3) & 3;           // N-slice 0..3
    const int m   = (bid & 7) + ((bid >> 5) << 3); // M-tile 0..63 (XCD-grouped)
    const int b0  = m * 32;
    unsigned* cnt = &cnts[m * CNT_STRIDE];
    unsigned phase = 0;

    // staging coords: thread -> (row srow, 32-wide k segment)
    const int srow = tid >> 3;                // 0..31
    const int kseg = (tid & 7) * 32;          // 0..224
    const int smt  = srow >> 4, slrow = srow & 15;

    f16* hbuf[2] = {hb0, hb1};

    // ---- persistent encoder weights: global(L2) -> VGPR, one-time ----
    f16x8 Bf[4][16];
#pragma unroll
    for (int f = 0; f < 4; ++f) {
        const int ct = n * 16 + w * 4 + f;
#pragma unroll
        for (int kk = 0; kk < 16; ++kk)
            Bf[f][kk] = *(const f16x8*)&WeP[((size_t)(ct * 16 + kk) * 64 + l) * 8];
    }

    // bias for this thread's j (= l) : gates at pb[n*256 + 4l .. +4]
    const f32x4 pbr = *(const f32x4*)&pb[n * 256 + l * 4];

    // c state: thread owns (row = 4i+w, j = l), i = 0..7
    float cs[8];
#pragma unroll
    for (int i = 0; i < 8; ++i) cs[i] = 0.f;

    const int q = l >> 4, c15 = l & 15;

    // prefetch x for t=0
    float4 xv[8];
    {
        const float* src = x0 + (size_t)(b0 + srow) * XROWSTRIDE + kseg;
#pragma unroll
        for (int qq = 0; qq < 8; ++qq) xv[qq] = *(const float4*)(src + qq * 4);
    }

    // ================= encoder: 64 steps, K = 512 =================
    for (int t = 0; t < S_; ++t) {
        // ---- stage A: x (regs->f16->LDS, kk 0..7) + h (global->LDS, kk 8..15)
        {
            const int kkA = kseg >> 5;
#pragma unroll
            for (int qq = 0; qq < 4; ++qq) {
                float4 v0 = xv[qq * 2], v1 = xv[qq * 2 + 1];
                f16x8 h8;
                h8[0]=(f16)v0.x; h8[1]=(f16)v0.y; h8[2]=(f16)v0.z; h8[3]=(f16)v0.w;
                h8[4]=(f16)v1.x; h8[5]=(f16)v1.y; h8[6]=(f16)v1.z; h8[7]=(f16)v1.w;
                *(f16x8*)&sA[sa_off(smt * 16 + kkA, qq * 16 + slrow)] = h8;
            }
            const f16* hsrc = hbuf[t & 1] + (size_t)(b0 + srow) * H_ + kseg;
            const int kkH = 8 + (kseg >> 5);
#pragma unroll
            for (int qq = 0; qq < 4; ++qq) {
                f16x8 h8 = *(const f16x8*)(hsrc + qq * 8);
                *(f16x8*)&sA[sa_off(smt * 16 + kkH, qq * 16 + slrow)] = h8;
            }
        }
        __syncthreads();

        // ---- MFMA: 128 per wave (2 mt x 4 f x 16 kk) ----
        f32x4 acc[2][4];
#pragma unroll
        for (int mt = 0; mt < 2; ++mt)
#pragma unroll
            for (int f = 0; f < 4; ++f) acc[mt][f] = (f32x4){0.f, 0.f, 0.f, 0.f};
#pragma unroll
        for (int kk = 0; kk < 16; ++kk) {
            f16x8 a0 = *(const f16x8*)&sA[sa_off(kk, l)];
            f16x8 a1 = *(const f16x8*)&sA[sa_off(16 + kk, l)];
#pragma unroll
            for (int f = 0; f < 4; ++f) {
                acc[0][f] = __builtin_amdgcn_mfma_f32_16x16x32_f16(a0, Bf[f][kk], acc[0][f], 0, 0, 0);
                acc[1][f] = __builtin_amdgcn_mfma_f32_16x16x32_f16(a1, Bf[f][kk], acc[1][f], 0, 0, 0);
            }
        }
        __syncthreads();   // sA dead; smem becomes sEpi

        // prefetch next x (completes by the fence's vmcnt drain at gsync)
        if (t + 1 < S_) {
            const float* src = x0 + (size_t)(b0 + srow) * XROWSTRIDE + (t + 1) * H_ + kseg;
#pragma unroll
            for (int qq = 0; qq < 8; ++qq) xv[qq] = *(const float4*)(src + qq * 4);
        }

        // ---- epilogue: C layout (col = c15, row = q*4+r) -> LDS ----
#pragma unroll
        for (int mt = 0; mt < 2; ++mt)
#pragma unroll
            for (int f = 0; f < 4; ++f)
#pragma unroll
                for (int r = 0; r < 4; ++r)
                    sEpi[(mt * 16 + q * 4 + r) * EPI_STRIDE + w * 64 + f * 16 + c15] = acc[mt][f][r];
        __syncthreads();

        // ---- fused cell: thread -> (row = 4i+w, j = l), lane-contig reads ----
        f16* hdst = hbuf[(t + 1) & 1];
#pragma unroll
        for (int i = 0; i < 8; ++i) {
            const int row = i * 4 + w;
            f32x4 g4 = *(const f32x4*)&sEpi[row * EPI_STRIDE + l * 4];
            float vi = g4[0] + pbr[0];
            float vf = g4[1] + pbr[1];
            float vg = g4[2] + pbr[2];
            float vo = g4[3] + pbr[3];
            float ig = sigm(vi), fg = sigm(vf), gg = tanh_(vg), og = sigm(vo);
            float cn = fg * cs[i] + ig * gg;
            float hn = og * tanh_(cn);
            cs[i] = cn;
            hdst[(size_t)(b0 + row) * H_ + n * 64 + l] = (f16)hn;
            if (t == S_ - 1)
                out[(size_t)(b0 + row) * (OUTS * H_) + n * 64 + l] = hn;
        }
        gsync(cnt, (++phase) * 4u);
    }

    // ---- swap in AR weights (pre-summed W_ih+W_hh), K = 256 ----
#pragma unroll
    for (int f = 0; f < 4; ++f) {
        const int ct = n * 16 + w * 4 + f;
#pragma unroll
        for (int kk = 0; kk < 8; ++kk)
            Bf[f][kk] = *(const f16x8*)&WaP[((size_t)(ct * 8 + kk) * 64 + l) * 8];
    }

    // ================= AR rollout: 32 steps, A = h, K = 256 =================
    for (int t = 0; t < NSTEP; ++t) {
        {
            const f16* hsrc = hbuf[t & 1] + (size_t)(b0 + srow) * H_ + kseg;
            const int kkH = kseg >> 5;
#pragma unroll
            for (int qq = 0; qq < 4; ++qq) {
                f16x8 h8 = *(const f16x8*)(hsrc + qq * 8);
                *(f16x8*)&sA[sa_off(smt * 8 + kkH, qq * 16 + slrow)] = h8;
            }
        }
        __syncthreads();

        f32x4 acc[2][4];
#pragma unroll
        for (int mt = 0; mt < 2; ++mt)
#pragma unroll
            for (int f = 0; f < 4; ++f) acc[mt][f] = (f32x4){0.f, 0.f, 0.f, 0.f};
#pragma unroll
        for (int kk = 0; kk < 8; ++kk) {
            f16x8 a0 = *(const f16x8*)&sA[sa_off(kk, l)];
            f16x8 a1 = *(const f16x8*)&sA[sa_off(8 + kk, l)];
#pragma unroll
            for (int f = 0; f < 4; ++f) {
                acc[0][f] = __builtin_amdgcn_mfma_f32_16x16x32_f16(a0, Bf[f][kk], acc[0][f], 0, 0, 0);
                acc[1][f] = __builtin_amdgcn_mfma_f32_16x16x32_f16(a1, Bf[f][kk], acc[1][f], 0, 0, 0);
            }
        }
        __syncthreads();

#pragma unroll
        for (int mt = 0; mt < 2; ++mt)
#pragma unroll
            for (int f = 0; f < 4; ++f)
#pragma unroll
                for (int r = 0; r < 4; ++r)
                    sEpi[(mt * 16 + q * 4 + r) * EPI_STRIDE + w * 64 + f * 16 + c15] = acc[mt][f][r];
        __syncthreads();

        f16* hdst = hbuf[(t + 1) & 1];
#pragma unroll
        for (int i = 0; i < 8; ++i) {
            const int row = i * 4 + w;
            f32x4 g4 = *(const f32x4*)&sEpi[row * EPI_STRIDE + l * 4];
            float vi = g4[0] + pbr[0];
            float vf = g4[1] + pbr[1];
            float vg = g4[2] + pbr[2];
            float vo = g4[3] + pbr[3];
            float ig = sigm(vi), fg = sigm(vf), gg = tanh_(vg), og = sigm(vo);
            float cn = fg * cs[i] + ig * gg;
            float hn = og * tanh_(cn);
            cs[i] = cn;
            hdst[(size_t)(b0 + row) * H_ + n * 64 + l] = (f16)hn;
            out[(size_t)(b0 + row) * (OUTS * H_) + (size_t)(t + 1) * H_ + n * 64 + l] = hn;
        }
        if (t + 1 < NSTEP) gsync(cnt, (++phase) * 4u);
    }
}

// ---------------------------------------------------------------------------
extern "C" void kernel_launch(void* const* d_in, const int* in_sizes, int n_in,
                              void* d_out, int out_size, void* d_ws, size_t ws_size,
                              hipStream_t stream) {
    const float* x0   = (const float*)d_in[0];
    const float* W_ih = (const float*)d_in[1];
    const float* W_hh = (const float*)d_in[2];
    const float* b_ih = (const float*)d_in[3];
    const float* b_hh = (const float*)d_in[4];
    float* out = (float*)d_out;

    // workspace (~3.6 MB)
    char* p = (char*)d_ws;
    f16* WeP = (f16*)p; p += (size_t)N4H * 512 * 2;
    f16* WaP = (f16*)p; p += (size_t)N4H * 256 * 2;
    float* pb = (float*)p; p += (size_t)N4H * 4;
    f16* hb0 = (f16*)p; p += (size_t)B_ * H_ * 2;
    f16* hb1 = (f16*)p; p += (size_t)B_ * H_ * 2;
    unsigned* cnts = (unsigned*)p; p += (size_t)64 * CNT_STRIDE * 4;

    hipMemsetAsync(hb0, 0, (size_t)B_ * H_ * 2, stream);
    hipMemsetAsync(cnts, 0, (size_t)64 * CNT_STRIDE * 4, stream);

    const int prep_total = N4H * 64 + N4H * 32 + N4H;
    prep_kernel<<<dim3((prep_total + 255) / 256), dim3(256), 0, stream>>>(
        W_ih, W_hh, b_ih, b_hh, WeP, WaP, pb);

    // persistent kernel, plain launch: 256 blocks (1/CU) x 256 threads
    lstm_fused<<<dim3(NBLK), dim3(256), 0, stream>>>(
        x0, WeP, WaP, pb, hb0, hb1, cnts, out);
}

// Round 4
// 706.967 us; speedup vs baseline: 2.8060x; 1.5500x over previous
//
#include <hip/hip_runtime.h>
#include <cstdint>
#include <cstddef>

// Problem constants
#define B_    2048
#define H_    256
#define S_    64
#define NSTEP 32
#define OUTS  33
#define N4H   1024            // 4*H gate cols, permuted n = j*4 + g
#define XROWSTRIDE (S_ * H_)  // x0 batch-row stride (fixed t)
#define EPI_STRIDE 260        // floats
#define NBLK  256
#define CNT_STRIDE 16         // u32s per group counter (64B line separation)

typedef _Float16 f16;
typedef _Float16 f16x4 __attribute__((ext_vector_type(4)));
typedef _Float16 f16x8 __attribute__((ext_vector_type(8)));
typedef float    f32x4 __attribute__((ext_vector_type(4)));

__device__ __forceinline__ float sigm(float x)  { return 1.f / (1.f + __expf(-x)); }
__device__ __forceinline__ float tanh_(float x) { return 1.f - 2.f / (1.f + __expf(2.f * x)); }

// Swizzled sA offset (f16 units). t16 = fragment-row, slot 0..63.
__device__ __forceinline__ int sa_off(int t16, int slot) {
    return (t16 * 64 + (slot ^ (t16 & 7))) * 8;
}

// Pin 8 f16x8 fragments into VGPRs: asm "writes" them, so the compiler can
// neither rematerialize the loads inside the loop nor sink them. With
// waves_per_eu(1,1) the allocator has 512 VGPRs -> no spill.
#define PIN8(A) asm volatile("" : "+v"((A)[0]), "+v"((A)[1]), "+v"((A)[2]), "+v"((A)[3]), \
                                  "+v"((A)[4]), "+v"((A)[5]), "+v"((A)[6]), "+v"((A)[7]))

// ---- cross-XCD h exchange through memory-side Infinity Cache (sc0 sc1) ----
// System-scope relaxed atomics bypass L1+L2 -> coherent across XCDs with NO
// cache-maintenance (no buffer_wbl2/buffer_inv). h is tiny (16KB/group/step).
__device__ __forceinline__ f16x4 ld_h8(const f16* p) {
    unsigned long long v = __hip_atomic_load((const unsigned long long*)p,
                                             __ATOMIC_RELAXED, __HIP_MEMORY_SCOPE_SYSTEM);
    return __builtin_bit_cast(f16x4, v);
}
__device__ __forceinline__ void st_h2(f16* p, f16 v) {
    __hip_atomic_store((unsigned short*)p, __builtin_bit_cast(unsigned short, v),
                       __ATOMIC_RELAXED, __HIP_MEMORY_SCOPE_SYSTEM);
}

// ---------------------------------------------------------------------------
// Group barrier: 4 blocks sharing an M-tile sync on one IF$-resident counter.
// NO fences: h stores are sc0sc1 write-through (visible once vmcnt retires),
// h loads are sc0sc1 (never stale). Bounded spin -> visible failure, no hang.
// ---------------------------------------------------------------------------
__device__ __forceinline__ void gsync(unsigned* cnt, unsigned target) {
    asm volatile("s_waitcnt vmcnt(0)" ::: "memory");  // all lanes: h stores in IF$
    __syncthreads();
    if (threadIdx.x == 0) {
        __hip_atomic_fetch_add(cnt, 1u, __ATOMIC_RELAXED, __HIP_MEMORY_SCOPE_SYSTEM);
        unsigned spins = 0;
        while (__hip_atomic_load(cnt, __ATOMIC_RELAXED, __HIP_MEMORY_SCOPE_SYSTEM) < target) {
            __builtin_amdgcn_s_sleep(1);
            if (++spins > (1u << 20)) break;   // fail-safe, never deadlock
        }
    }
    __syncthreads();
    asm volatile("" ::: "memory");
}

// ---------------------------------------------------------------------------
// Prep: quantize + pack weights into MFMA-B-fragment-major f16 layout:
//   dest[((ct*KT + kk)*64 + q*16 + c15)*8 + e] = W[n = ct*16+c15][k = kk*32+q*8+e]
//   WeP: encoder, KT=16, k in [0,512) = [W_ih | W_hh], n permuted j*4+g
//   WaP: AR, KT=8, W_ih + W_hh pre-summed (x == h in AR phase)
//   pb : permuted bias sum
// ---------------------------------------------------------------------------
__global__ __launch_bounds__(256) void prep_kernel(
    const float* __restrict__ W_ih, const float* __restrict__ W_hh,
    const float* __restrict__ b_ih, const float* __restrict__ b_hh,
    f16* __restrict__ WeP, f16* __restrict__ WaP, float* __restrict__ pb)
{
    int t = blockIdx.x * 256 + threadIdx.x;
    if (t < N4H * 64) {                 // encoder pack: 8 elems/thread
        int n  = t >> 6;                // permuted col 0..1023
        int kc = (t & 63) * 8;          // k base 0..504
        int j = n >> 2, g = n & 3;
        const float* src = (kc < H_) ? &W_ih[(size_t)(g * H_ + j) * H_ + kc]
                                     : &W_hh[(size_t)(g * H_ + j) * H_ + kc - H_];
        f16x8 v;
#pragma unroll
        for (int e = 0; e < 8; ++e) v[e] = (f16)src[e];
        int ct = n >> 4, c15 = n & 15, kk = kc >> 5, q = (kc >> 3) & 3;
        *(f16x8*)&WeP[((size_t)(ct * 16 + kk) * 64 + q * 16 + c15) * 8] = v;
    } else if (t < N4H * 64 + N4H * 32) {   // AR pack (Wsum), KT=8
        int u  = t - N4H * 64;
        int n  = u >> 5;
        int kc = (u & 31) * 8;
        int j = n >> 2, g = n & 3;
        const float* s1 = &W_ih[(size_t)(g * H_ + j) * H_ + kc];
        const float* s2 = &W_hh[(size_t)(g * H_ + j) * H_ + kc];
        f16x8 v;
#pragma unroll
        for (int e = 0; e < 8; ++e) v[e] = (f16)(s1[e] + s2[e]);
        int ct = n >> 4, c15 = n & 15, kk = kc >> 5, q = (kc >> 3) & 3;
        *(f16x8*)&WaP[((size_t)(ct * 8 + kk) * 64 + q * 16 + c15) * 8] = v;
    } else if (t < N4H * 64 + N4H * 32 + N4H) {
        int n = t - (N4H * 64 + N4H * 32);
        int j = n >> 2, g = n & 3;
        pb[n] = b_ih[g * H_ + j] + b_hh[g * H_ + j];
    }
}

// ---------------------------------------------------------------------------
// Persistent LSTM, plain launch: one kernel, 96 steps, 4-block group sync.
//   Grid: 256 blocks x 256 threads, 1 block/CU, 1 wave/SIMD (full 512-VGPR
//   budget via amdgpu_waves_per_eu(1,1)).
//   Block (m,n): rows m*32..+32, gate cols n*256..+256. Wave owns 64 cols.
//   - Encoder B fragments Bf[4][16] = 256 VGPRs/lane, PINNED via asm ->
//     loaded once, never re-read (round-3 failure mode: remat per step).
//   - h exchanged via IF$ (sc0sc1) -> no L2 writeback/invalidate per step;
//     x0 and weights stay L2-cached for the whole kernel.
//   - c in 8 VGPRs/thread; x_{t+1} prefetched under the epilogue.
// ---------------------------------------------------------------------------
__global__ __attribute__((amdgpu_waves_per_eu(1, 1))) __launch_bounds__(256)
void lstm_fused(
    const float* __restrict__ x0,
    const f16*  __restrict__ WeP,
    const f16*  __restrict__ WaP,
    const float* __restrict__ pb,
    f16* __restrict__ hb0, f16* __restrict__ hb1,
    unsigned* __restrict__ cnts,
    float* __restrict__ out)
{
    __shared__ __align__(16) unsigned char smem[32 * EPI_STRIDE * 4]; // 33.3 KB
    f16*   sA   = (f16*)smem;    // staged A tile (32 rows x K), frag-major
    float* sEpi = (float*)smem;  // gate tile 32 x 256 (overlaid, barrier-separated)

    const int tid = threadIdx.x;
    const int l   = tid & 63;
    const int w   = tid >> 6;                 // wave 0..3
    const int bid = blockIdx.x;
    const int n   = (bid >> 3) & 3;           // N-slice 0..3
    const int m   = (bid & 7) + ((bid >> 5) << 3); // M-tile 0..63 (XCD-grouped)
    const int b0  = m * 32;
    unsigned* cnt = &cnts[m * CNT_STRIDE];
    unsigned phase = 0;

    // staging coords: thread -> (row srow, 32-wide k segment)
    const int srow = tid >> 3;                // 0..31
    const int kseg = (tid & 7) * 32;          // 0..224
    const int smt  = srow >> 4, slrow = srow & 15;

    f16* hbuf[2] = {hb0, hb1};

    // ---- persistent encoder weights: global(L2) -> VGPR, one-time, PINNED ----
    f16x8 Bf[4][16];
#pragma unroll
    for (int f = 0; f < 4; ++f) {
        const int ct = n * 16 + w * 4 + f;
#pragma unroll
        for (int kk = 0; kk < 16; ++kk)
            Bf[f][kk] = *(const f16x8*)&WeP[((size_t)(ct * 16 + kk) * 64 + l) * 8];
    }
#pragma unroll
    for (int f = 0; f < 4; ++f) { PIN8(&Bf[f][0]); PIN8(&Bf[f][8]); }

    // bias for this thread's j (= l) : gates at pb[n*256 + 4l .. +4]
    const f32x4 pbr = *(const f32x4*)&pb[n * 256 + l * 4];

    // c state: thread owns (row = 4i+w, j = l), i = 0..7
    float cs[8];
#pragma unroll
    for (int i = 0; i < 8; ++i) cs[i] = 0.f;

    const int q = l >> 4, c15 = l & 15;

    // prefetch x for t=0
    float4 xv[8];
    {
        const float* src = x0 + (size_t)(b0 + srow) * XROWSTRIDE + kseg;
#pragma unroll
        for (int qq = 0; qq < 8; ++qq) xv[qq] = *(const float4*)(src + qq * 4);
    }

    // ================= encoder: 64 steps, K = 512 =================
    for (int t = 0; t < S_; ++t) {
        // ---- stage A: x (regs->f16->LDS, kk 0..7) + h (IF$->LDS, kk 8..15)
        {
            const int kkA = kseg >> 5;
#pragma unroll
            for (int qq = 0; qq < 4; ++qq) {
                float4 v0 = xv[qq * 2], v1 = xv[qq * 2 + 1];
                f16x8 h8;
                h8[0]=(f16)v0.x; h8[1]=(f16)v0.y; h8[2]=(f16)v0.z; h8[3]=(f16)v0.w;
                h8[4]=(f16)v1.x; h8[5]=(f16)v1.y; h8[6]=(f16)v1.z; h8[7]=(f16)v1.w;
                *(f16x8*)&sA[sa_off(smt * 16 + kkA, qq * 16 + slrow)] = h8;
            }
            const f16* hsrc = hbuf[t & 1] + (size_t)(b0 + srow) * H_ + kseg;
            const int kkH = 8 + (kseg >> 5);
#pragma unroll
            for (int qq = 0; qq < 4; ++qq) {
                f16x4 lo = ld_h8(hsrc + qq * 8);
                f16x4 hi = ld_h8(hsrc + qq * 8 + 4);
                f16x8 h8;
#pragma unroll
                for (int e = 0; e < 4; ++e) { h8[e] = lo[e]; h8[4 + e] = hi[e]; }
                *(f16x8*)&sA[sa_off(smt * 16 + kkH, qq * 16 + slrow)] = h8;
            }
        }
        __syncthreads();

        // ---- MFMA: 128 per wave (2 mt x 4 f x 16 kk) ----
        f32x4 acc[2][4];
#pragma unroll
        for (int mt = 0; mt < 2; ++mt)
#pragma unroll
            for (int f = 0; f < 4; ++f) acc[mt][f] = (f32x4){0.f, 0.f, 0.f, 0.f};
#pragma unroll
        for (int kk = 0; kk < 16; ++kk) {
            f16x8 a0 = *(const f16x8*)&sA[sa_off(kk, l)];
            f16x8 a1 = *(const f16x8*)&sA[sa_off(16 + kk, l)];
#pragma unroll
            for (int f = 0; f < 4; ++f) {
                acc[0][f] = __builtin_amdgcn_mfma_f32_16x16x32_f16(a0, Bf[f][kk], acc[0][f], 0, 0, 0);
                acc[1][f] = __builtin_amdgcn_mfma_f32_16x16x32_f16(a1, Bf[f][kk], acc[1][f], 0, 0, 0);
            }
        }
        __syncthreads();   // sA dead; smem becomes sEpi

        // prefetch next x (plain cached loads; completes under epilogue/cell)
        if (t + 1 < S_) {
            const float* src = x0 + (size_t)(b0 + srow) * XROWSTRIDE + (t + 1) * H_ + kseg;
#pragma unroll
            for (int qq = 0; qq < 8; ++qq) xv[qq] = *(const float4*)(src + qq * 4);
        }

        // ---- epilogue: C layout (col = c15, row = q*4+r) -> LDS ----
#pragma unroll
        for (int mt = 0; mt < 2; ++mt)
#pragma unroll
            for (int f = 0; f < 4; ++f)
#pragma unroll
                for (int r = 0; r < 4; ++r)
                    sEpi[(mt * 16 + q * 4 + r) * EPI_STRIDE + w * 64 + f * 16 + c15] = acc[mt][f][r];
        __syncthreads();

        // ---- fused cell: thread -> (row = 4i+w, j = l), lane-contig reads ----
        f16* hdst = hbuf[(t + 1) & 1];
#pragma unroll
        for (int i = 0; i < 8; ++i) {
            const int row = i * 4 + w;
            f32x4 g4 = *(const f32x4*)&sEpi[row * EPI_STRIDE + l * 4];
            float vi = g4[0] + pbr[0];
            float vf = g4[1] + pbr[1];
            float vg = g4[2] + pbr[2];
            float vo = g4[3] + pbr[3];
            float ig = sigm(vi), fg = sigm(vf), gg = tanh_(vg), og = sigm(vo);
            float cn = fg * cs[i] + ig * gg;
            float hn = og * tanh_(cn);
            cs[i] = cn;
            st_h2(&hdst[(size_t)(b0 + row) * H_ + n * 64 + l], (f16)hn);
            if (t == S_ - 1)
                out[(size_t)(b0 + row) * (OUTS * H_) + n * 64 + l] = hn;
        }
        gsync(cnt, (++phase) * 4u);
    }

    // ---- swap in AR weights (pre-summed W_ih+W_hh), K = 256, re-pin ----
#pragma unroll
    for (int f = 0; f < 4; ++f) {
        const int ct = n * 16 + w * 4 + f;
#pragma unroll
        for (int kk = 0; kk < 8; ++kk)
            Bf[f][kk] = *(const f16x8*)&WaP[((size_t)(ct * 8 + kk) * 64 + l) * 8];
    }
#pragma unroll
    for (int f = 0; f < 4; ++f) PIN8(&Bf[f][0]);

    // ================= AR rollout: 32 steps, A = h, K = 256 =================
    for (int t = 0; t < NSTEP; ++t) {
        {
            const f16* hsrc = hbuf[t & 1] + (size_t)(b0 + srow) * H_ + kseg;
            const int kkH = kseg >> 5;
#pragma unroll
            for (int qq = 0; qq < 4; ++qq) {
                f16x4 lo = ld_h8(hsrc + qq * 8);
                f16x4 hi = ld_h8(hsrc + qq * 8 + 4);
                f16x8 h8;
#pragma unroll
                for (int e = 0; e < 4; ++e) { h8[e] = lo[e]; h8[4 + e] = hi[e]; }
                *(f16x8*)&sA[sa_off(smt * 8 + kkH, qq * 16 + slrow)] = h8;
            }
        }
        __syncthreads();

        f32x4 acc[2][4];
#pragma unroll
        for (int mt = 0; mt < 2; ++mt)
#pragma unroll
            for (int f = 0; f < 4; ++f) acc[mt][f] = (f32x4){0.f, 0.f, 0.f, 0.f};
#pragma unroll
        for (int kk = 0; kk < 8; ++kk) {
            f16x8 a0 = *(const f16x8*)&sA[sa_off(kk, l)];
            f16x8 a1 = *(const f16x8*)&sA[sa_off(8 + kk, l)];
#pragma unroll
            for (int f = 0; f < 4; ++f) {
                acc[0][f] = __builtin_amdgcn_mfma_f32_16x16x32_f16(a0, Bf[f][kk], acc[0][f], 0, 0, 0);
                acc[1][f] = __builtin_amdgcn_mfma_f32_16x16x32_f16(a1, Bf[f][kk], acc[1][f], 0, 0, 0);
            }
        }
        __syncthreads();

#pragma unroll
        for (int mt = 0; mt < 2; ++mt)
#pragma unroll
            for (int f = 0; f < 4; ++f)
#pragma unroll
                for (int r = 0; r < 4; ++r)
                    sEpi[(mt * 16 + q * 4 + r) * EPI_STRIDE + w * 64 + f * 16 + c15] = acc[mt][f][r];
        __syncthreads();

        f16* hdst = hbuf[(t + 1) & 1];
#pragma unroll
        for (int i = 0; i < 8; ++i) {
            const int row = i * 4 + w;
            f32x4 g4 = *(const f32x4*)&sEpi[row * EPI_STRIDE + l * 4];
            float vi = g4[0] + pbr[0];
            float vf = g4[1] + pbr[1];
            float vg = g4[2] + pbr[2];
            float vo = g4[3] + pbr[3];
            float ig = sigm(vi), fg = sigm(vf), gg = tanh_(vg), og = sigm(vo);
            float cn = fg * cs[i] + ig * gg;
            float hn = og * tanh_(cn);
            cs[i] = cn;
            st_h2(&hdst[(size_t)(b0 + row) * H_ + n * 64 + l], (f16)hn);
            out[(size_t)(b0 + row) * (OUTS * H_) + (size_t)(t + 1) * H_ + n * 64 + l] = hn;
        }
        if (t + 1 < NSTEP) gsync(cnt, (++phase) * 4u);
    }
}

// ---------------------------------------------------------------------------
extern "C" void kernel_launch(void* const* d_in, const int* in_sizes, int n_in,
                              void* d_out, int out_size, void* d_ws, size_t ws_size,
                              hipStream_t stream) {
    const float* x0   = (const float*)d_in[0];
    const float* W_ih = (const float*)d_in[1];
    const float* W_hh = (const float*)d_in[2];
    const float* b_ih = (const float*)d_in[3];
    const float* b_hh = (const float*)d_in[4];
    float* out = (float*)d_out;

    // workspace (~3.6 MB)
    char* p = (char*)d_ws;
    f16* WeP = (f16*)p; p += (size_t)N4H * 512 * 2;
    f16* WaP = (f16*)p; p += (size_t)N4H * 256 * 2;
    float* pb = (float*)p; p += (size_t)N4H * 4;
    f16* hb0 = (f16*)p; p += (size_t)B_ * H_ * 2;
    f16* hb1 = (f16*)p; p += (size_t)B_ * H_ * 2;
    unsigned* cnts = (unsigned*)p; p += (size_t)64 * CNT_STRIDE * 4;

    hipMemsetAsync(hb0, 0, (size_t)B_ * H_ * 2, stream);
    hipMemsetAsync(cnts, 0, (size_t)64 * CNT_STRIDE * 4, stream);

    const int prep_total = N4H * 64 + N4H * 32 + N4H;
    prep_kernel<<<dim3((prep_total + 255) / 256), dim3(256), 0, stream>>>(
        W_ih, W_hh, b_ih, b_hh, WeP, WaP, pb);

    // persistent kernel, plain launch: 256 blocks (1/CU) x 256 threads
    lstm_fused<<<dim3(NBLK), dim3(256), 0, stream>>>(
        x0, WeP, WaP, pb, hb0, hb1, cnts, out);
}

// Round 5
// 612.684 us; speedup vs baseline: 3.2379x; 1.1539x over previous
//
#include <hip/hip_runtime.h>
#include <cstdint>
#include <cstddef>

// Problem constants
#define B_    2048
#define H_    256
#define S_    64
#define NSTEP 32
#define OUTS  33
#define N4H   1024            // 4*H gate cols, permuted n = j*4 + g
#define XROWSTRIDE (S_ * H_)  // x0 batch-row stride (fixed t)
#define EPI_STRIDE 268        // floats: 4*268%32==16 -> epi writes 2-way(free);
                              // cell f32x4 reads spread over all 8 bank-quads
#define NBLK  256
#define CNT_STRIDE 16         // u32s per group counter (64B line separation)

typedef _Float16 f16;
typedef _Float16 f16x4 __attribute__((ext_vector_type(4)));
typedef _Float16 f16x8 __attribute__((ext_vector_type(8)));
typedef float    f32x4 __attribute__((ext_vector_type(4)));
typedef unsigned long long u64;

__device__ __forceinline__ float sigm(float x)  { return 1.f / (1.f + __expf(-x)); }
__device__ __forceinline__ float tanh_(float x) { return 1.f - 2.f / (1.f + __expf(2.f * x)); }

// A-tile LDS layout: frag-row t16 = mt*8 + kk holds 64 slots of 16B (one lane
// fragment each). XOR slot^((t16&7)<<2): reads get a uniform-per-t16 lane
// permutation (conflict-free b128); staging writes (slot = q*16 + c15 with
// c15 4-aligned-consecutive per wave, kk varying across lanes) land on 32
// distinct 16B slots per instruction -> bank-floor. Derivation in r5 notes.
__device__ __forceinline__ int sa2(int t16, int slot) {
    return (t16 * 64 + (slot ^ ((t16 & 7) << 2))) * 8;
}

// Pin weight fragments into VGPRs (no remat/sink of the loads).
#define PIN8(A) asm volatile("" : "+v"((A)[0]), "+v"((A)[1]), "+v"((A)[2]), "+v"((A)[3]), \
                                  "+v"((A)[4]), "+v"((A)[5]), "+v"((A)[6]), "+v"((A)[7]))
#define PIN4(A) asm volatile("" : "+v"((A)[0]), "+v"((A)[1]), "+v"((A)[2]), "+v"((A)[3]))

// ---- cross-XCD h exchange through memory-side Infinity Cache (sc0 sc1) ----
__device__ __forceinline__ u64 ld64sys(const f16* p) {
    return __hip_atomic_load((const u64*)p, __ATOMIC_RELAXED, __HIP_MEMORY_SCOPE_SYSTEM);
}
__device__ __forceinline__ void st64sys(f16* p, u64 v) {
    __hip_atomic_store((u64*)p, v, __ATOMIC_RELAXED, __HIP_MEMORY_SCOPE_SYSTEM);
}
__device__ __forceinline__ f16x8 pack8(u64 a, u64 b) {
    f16x4 x = __builtin_bit_cast(f16x4, a), y = __builtin_bit_cast(f16x4, b);
    f16x8 r;
    r[0] = x[0]; r[1] = x[1]; r[2] = x[2]; r[3] = x[3];
    r[4] = y[0]; r[5] = y[1]; r[6] = y[2]; r[7] = y[3];
    return r;
}

// ---------------------------------------------------------------------------
// Prep (unchanged, proven): pack weights MFMA-B-fragment-major.
// ---------------------------------------------------------------------------
__global__ __launch_bounds__(256) void prep_kernel(
    const float* __restrict__ W_ih, const float* __restrict__ W_hh,
    const float* __restrict__ b_ih, const float* __restrict__ b_hh,
    f16* __restrict__ WeP, f16* __restrict__ WaP, float* __restrict__ pb)
{
    int t = blockIdx.x * 256 + threadIdx.x;
    if (t < N4H * 64) {                 // encoder pack: 8 elems/thread
        int n  = t >> 6;
        int kc = (t & 63) * 8;
        int j = n >> 2, g = n & 3;
        const float* src = (kc < H_) ? &W_ih[(size_t)(g * H_ + j) * H_ + kc]
                                     : &W_hh[(size_t)(g * H_ + j) * H_ + kc - H_];
        f16x8 v;
#pragma unroll
        for (int e = 0; e < 8; ++e) v[e] = (f16)src[e];
        int ct = n >> 4, c15 = n & 15, kk = kc >> 5, q = (kc >> 3) & 3;
        *(f16x8*)&WeP[((size_t)(ct * 16 + kk) * 64 + q * 16 + c15) * 8] = v;
    } else if (t < N4H * 64 + N4H * 32) {   // AR pack (Wsum), KT=8
        int u  = t - N4H * 64;
        int n  = u >> 5;
        int kc = (u & 31) * 8;
        int j = n >> 2, g = n & 3;
        const float* s1 = &W_ih[(size_t)(g * H_ + j) * H_ + kc];
        const float* s2 = &W_hh[(size_t)(g * H_ + j) * H_ + kc];
        f16x8 v;
#pragma unroll
        for (int e = 0; e < 8; ++e) v[e] = (f16)(s1[e] + s2[e]);
        int ct = n >> 4, c15 = n & 15, kk = kc >> 5, q = (kc >> 3) & 3;
        *(f16x8*)&WaP[((size_t)(ct * 8 + kk) * 64 + q * 16 + c15) * 8] = v;
    } else if (t < N4H * 64 + N4H * 32 + N4H) {
        int n = t - (N4H * 64 + N4H * 32);
        int j = n >> 2, g = n & 3;
        pb[n] = b_ih[g * H_ + j] + b_hh[g * H_ + j];
    }
}

// ---------------------------------------------------------------------------
// Persistent LSTM: 256 blocks x 512 threads (8 waves, 2/SIMD -> TLP).
//   Block (m,n): rows m*32..+32, gate cols n*256..+256.
//   Wave w: wp = w&3 owns 64 cols; half = w>>2 owns kk parity (kk = 2j+half)
//     -> weight slice = 128 VGPRs/lane (fits the 256-VGPR cap at 2 waves/EU).
//   Two halves write partial gates to sEpi[half]; cell sums them.
//   Pipeline: x-part MFMAs of step t+1 run between gsync-arrive and -spin,
//   so the critical path per step is only {h load -> 32 h-MFMAs -> cell}.
//   h exchanged via IF$ (sc0sc1), c in 4 VGPRs/thread, 4-block group sync.
// ---------------------------------------------------------------------------
__global__ __attribute__((amdgpu_waves_per_eu(2, 2))) __launch_bounds__(512)
void lstm_fused(
    const float* __restrict__ x0,
    const f16*  __restrict__ WeP,
    const f16*  __restrict__ WaP,
    const float* __restrict__ pb,
    f16* __restrict__ hb0, f16* __restrict__ hb1,
    unsigned* __restrict__ cnts,
    float* __restrict__ out)
{
    __shared__ __align__(16) f16   sAx[16 * 64 * 8];             // 16 KB
    __shared__ __align__(16) f16   sAh[16 * 64 * 8];             // 16 KB
    __shared__ __align__(16) float sEpi[2][32][EPI_STRIDE];      // 68.6 KB

    const int tid  = threadIdx.x;
    const int l    = tid & 63;
    const int w    = tid >> 6;                // 0..7
    const int wp   = w & 3;                   // col sub-slice (64 cols)
    const int half = w >> 2;                  // kk parity
    const int bid  = blockIdx.x;
    const int n    = (bid >> 3) & 3;
    const int m    = (bid & 7) + ((bid >> 5) << 3);   // XCD-grouped
    const int b0   = m * 32;
    unsigned* cnt  = &cnts[m * CNT_STRIDE];
    unsigned phase = 0;

    // staging map: thread -> (row srow, 32B chunk)
    const int srow  = tid >> 4;               // 0..31
    const int chunk = tid & 15;               // 16 f16 each
    const int s_c15 = srow & 15, s_mt = srow >> 4;
    const int s_kk  = chunk >> 1, s_q2 = chunk & 1;
    // cell map: thread -> (row crow, 4 consecutive local j)
    const int crow = tid >> 4;
    const int jl4  = (tid & 15) * 4;
    // MFMA epi coords
    const int q4 = (l >> 4) * 4, c15 = l & 15;

    f16* hbuf[2] = {hb0, hb1};

    // ---- persistent weights: wave's kk-parity slice, pinned ----
    f16x8 Bf[4][8];
#pragma unroll
    for (int f = 0; f < 4; ++f) {
        const int ct = n * 16 + wp * 4 + f;
#pragma unroll
        for (int jj = 0; jj < 8; ++jj) {
            const int kk = 2 * jj + half;
            Bf[f][jj] = *(const f16x8*)&WeP[((size_t)(ct * 16 + kk) * 64 + l) * 8];
        }
    }
#pragma unroll
    for (int f = 0; f < 4; ++f) PIN8(&Bf[f][0]);

    // c state: thread owns (crow, j = jl4..jl4+3)
    float cs[4] = {0.f, 0.f, 0.f, 0.f};

    f32x4 acc[2][4];

    // ---- prologue: stage x_0, compute x-part(0) ----
    {
        const float* xs = x0 + (size_t)(b0 + srow) * XROWSTRIDE + chunk * 16;
        float4 v0 = *(const float4*)(xs + 0), v1 = *(const float4*)(xs + 4);
        float4 v2 = *(const float4*)(xs + 8), v3 = *(const float4*)(xs + 12);
        f16x8 lo, hi;
        lo[0]=(f16)v0.x; lo[1]=(f16)v0.y; lo[2]=(f16)v0.z; lo[3]=(f16)v0.w;
        lo[4]=(f16)v1.x; lo[5]=(f16)v1.y; lo[6]=(f16)v1.z; lo[7]=(f16)v1.w;
        hi[0]=(f16)v2.x; hi[1]=(f16)v2.y; hi[2]=(f16)v2.z; hi[3]=(f16)v2.w;
        hi[4]=(f16)v3.x; hi[5]=(f16)v3.y; hi[6]=(f16)v3.z; hi[7]=(f16)v3.w;
        *(f16x8*)&sAx[sa2(s_mt * 8 + s_kk, (s_q2 * 2 + 0) * 16 + s_c15)] = lo;
        *(f16x8*)&sAx[sa2(s_mt * 8 + s_kk, (s_q2 * 2 + 1) * 16 + s_c15)] = hi;
    }
    __syncthreads();
#pragma unroll
    for (int mt = 0; mt < 2; ++mt)
#pragma unroll
        for (int f = 0; f < 4; ++f) acc[mt][f] = (f32x4){0.f, 0.f, 0.f, 0.f};
#pragma unroll
    for (int jj = 0; jj < 4; ++jj) {
        const int kk = 2 * jj + half;
        f16x8 a0 = *(const f16x8*)&sAx[sa2(0 * 8 + kk, l)];
        f16x8 a1 = *(const f16x8*)&sAx[sa2(1 * 8 + kk, l)];
#pragma unroll
        for (int f = 0; f < 4; ++f) {
            acc[0][f] = __builtin_amdgcn_mfma_f32_16x16x32_f16(a0, Bf[f][jj], acc[0][f], 0, 0, 0);
            acc[1][f] = __builtin_amdgcn_mfma_f32_16x16x32_f16(a1, Bf[f][jj], acc[1][f], 0, 0, 0);
        }
    }

    // ================= encoder: 64 steps =================
    for (int t = 0; t < S_; ++t) {
        // 1-2: h_t (IF$) -> sAh
        {
            const f16* hsrc = hbuf[t & 1] + (size_t)(b0 + srow) * H_ + chunk * 16;
            u64 d0 = ld64sys(hsrc + 0), d1 = ld64sys(hsrc + 4);
            u64 d2 = ld64sys(hsrc + 8), d3 = ld64sys(hsrc + 12);
            *(f16x8*)&sAh[sa2(s_mt * 8 + s_kk, (s_q2 * 2 + 0) * 16 + s_c15)] = pack8(d0, d1);
            *(f16x8*)&sAh[sa2(s_mt * 8 + s_kk, (s_q2 * 2 + 1) * 16 + s_c15)] = pack8(d2, d3);
        }
        __syncthreads();

        // 3: h-part MFMAs (32/wave) into acc (already holds x-part(t))
#pragma unroll
        for (int jj = 0; jj < 4; ++jj) {
            const int kkh = 2 * jj + half;
            f16x8 a0 = *(const f16x8*)&sAh[sa2(0 * 8 + kkh, l)];
            f16x8 a1 = *(const f16x8*)&sAh[sa2(1 * 8 + kkh, l)];
#pragma unroll
            for (int f = 0; f < 4; ++f) {
                acc[0][f] = __builtin_amdgcn_mfma_f32_16x16x32_f16(a0, Bf[f][4 + jj], acc[0][f], 0, 0, 0);
                acc[1][f] = __builtin_amdgcn_mfma_f32_16x16x32_f16(a1, Bf[f][4 + jj], acc[1][f], 0, 0, 0);
            }
        }

        // 4: epilogue partials
#pragma unroll
        for (int mt = 0; mt < 2; ++mt)
#pragma unroll
            for (int f = 0; f < 4; ++f)
#pragma unroll
                for (int r = 0; r < 4; ++r)
                    sEpi[half][mt * 16 + q4 + r][wp * 64 + f * 16 + c15] = acc[mt][f][r];
        __syncthreads();

        // 5: fused cell (sum halves), h -> IF$
        {
            f16* hdst = hbuf[(t + 1) & 1];
            const float* pbb = pb + n * 256 + jl4 * 4;
            float hvv[4];
            f16x4 hf;
#pragma unroll
            for (int jj = 0; jj < 4; ++jj) {
                f32x4 ga = *(const f32x4*)&sEpi[0][crow][(jl4 + jj) * 4];
                f32x4 gb = *(const f32x4*)&sEpi[1][crow][(jl4 + jj) * 4];
                f32x4 pv = *(const f32x4*)&pbb[jj * 4];
                float vi = ga[0] + gb[0] + pv[0];
                float vf = ga[1] + gb[1] + pv[1];
                float vg = ga[2] + gb[2] + pv[2];
                float vo = ga[3] + gb[3] + pv[3];
                float ig = sigm(vi), fg = sigm(vf), gg = tanh_(vg), og = sigm(vo);
                float cn = fg * cs[jj] + ig * gg;
                float hn = og * tanh_(cn);
                cs[jj] = cn; hvv[jj] = hn; hf[jj] = (f16)hn;
            }
            st64sys(&hdst[(size_t)(b0 + crow) * H_ + n * 64 + jl4],
                    __builtin_bit_cast(u64, hf));
            if (t == S_ - 1) {
                float4 o = {hvv[0], hvv[1], hvv[2], hvv[3]};
                *(float4*)&out[(size_t)(b0 + crow) * (OUTS * H_) + n * 64 + jl4] = o;
            }
        }

        // 6: arrive
        ++phase;
        asm volatile("s_waitcnt vmcnt(0)" ::: "memory");
        __syncthreads();
        if (tid == 0)
            __hip_atomic_fetch_add(cnt, 1u, __ATOMIC_RELAXED, __HIP_MEMORY_SCOPE_SYSTEM);

        // 7: tail (hidden in sync window): stage x_{t+1}, x-part MFMAs
        if (t + 1 < S_) {
            {
                const float* xs = x0 + (size_t)(b0 + srow) * XROWSTRIDE + (t + 1) * H_ + chunk * 16;
                float4 v0 = *(const float4*)(xs + 0), v1 = *(const float4*)(xs + 4);
                float4 v2 = *(const float4*)(xs + 8), v3 = *(const float4*)(xs + 12);
                f16x8 lo, hi;
                lo[0]=(f16)v0.x; lo[1]=(f16)v0.y; lo[2]=(f16)v0.z; lo[3]=(f16)v0.w;
                lo[4]=(f16)v1.x; lo[5]=(f16)v1.y; lo[6]=(f16)v1.z; lo[7]=(f16)v1.w;
                hi[0]=(f16)v2.x; hi[1]=(f16)v2.y; hi[2]=(f16)v2.z; hi[3]=(f16)v2.w;
                hi[4]=(f16)v3.x; hi[5]=(f16)v3.y; hi[6]=(f16)v3.z; hi[7]=(f16)v3.w;
                *(f16x8*)&sAx[sa2(s_mt * 8 + s_kk, (s_q2 * 2 + 0) * 16 + s_c15)] = lo;
                *(f16x8*)&sAx[sa2(s_mt * 8 + s_kk, (s_q2 * 2 + 1) * 16 + s_c15)] = hi;
            }
            __syncthreads();
#pragma unroll
            for (int mt = 0; mt < 2; ++mt)
#pragma unroll
                for (int f = 0; f < 4; ++f) acc[mt][f] = (f32x4){0.f, 0.f, 0.f, 0.f};
#pragma unroll
            for (int jj = 0; jj < 4; ++jj) {
                const int kk = 2 * jj + half;
                f16x8 a0 = *(const f16x8*)&sAx[sa2(0 * 8 + kk, l)];
                f16x8 a1 = *(const f16x8*)&sAx[sa2(1 * 8 + kk, l)];
#pragma unroll
                for (int f = 0; f < 4; ++f) {
                    acc[0][f] = __builtin_amdgcn_mfma_f32_16x16x32_f16(a0, Bf[f][jj], acc[0][f], 0, 0, 0);
                    acc[1][f] = __builtin_amdgcn_mfma_f32_16x16x32_f16(a1, Bf[f][jj], acc[1][f], 0, 0, 0);
                }
            }
        }

        // 8: spin + release
        if (tid == 0) {
            unsigned spins = 0;
            while (__hip_atomic_load(cnt, __ATOMIC_RELAXED, __HIP_MEMORY_SCOPE_SYSTEM) < phase * 4u) {
                __builtin_amdgcn_s_sleep(1);
                if (++spins > (1u << 20)) break;   // fail-safe, never deadlock
            }
        }
        __syncthreads();
    }

    // ---- swap in AR weights (pre-summed), K = 256 ----
#pragma unroll
    for (int f = 0; f < 4; ++f) {
        const int ct = n * 16 + wp * 4 + f;
#pragma unroll
        for (int jj = 0; jj < 4; ++jj) {
            const int kk = 2 * jj + half;
            Bf[f][jj] = *(const f16x8*)&WaP[((size_t)(ct * 8 + kk) * 64 + l) * 8];
        }
    }
#pragma unroll
    for (int f = 0; f < 4; ++f) PIN4(&Bf[f][0]);

    // ================= AR rollout: 32 steps =================
    for (int t = 0; t < NSTEP; ++t) {
        {
            const f16* hsrc = hbuf[t & 1] + (size_t)(b0 + srow) * H_ + chunk * 16;
            u64 d0 = ld64sys(hsrc + 0), d1 = ld64sys(hsrc + 4);
            u64 d2 = ld64sys(hsrc + 8), d3 = ld64sys(hsrc + 12);
            *(f16x8*)&sAh[sa2(s_mt * 8 + s_kk, (s_q2 * 2 + 0) * 16 + s_c15)] = pack8(d0, d1);
            *(f16x8*)&sAh[sa2(s_mt * 8 + s_kk, (s_q2 * 2 + 1) * 16 + s_c15)] = pack8(d2, d3);
        }
        __syncthreads();

#pragma unroll
        for (int mt = 0; mt < 2; ++mt)
#pragma unroll
            for (int f = 0; f < 4; ++f) acc[mt][f] = (f32x4){0.f, 0.f, 0.f, 0.f};
#pragma unroll
        for (int jj = 0; jj < 4; ++jj) {
            const int kk = 2 * jj + half;
            f16x8 a0 = *(const f16x8*)&sAh[sa2(0 * 8 + kk, l)];
            f16x8 a1 = *(const f16x8*)&sAh[sa2(1 * 8 + kk, l)];
#pragma unroll
            for (int f = 0; f < 4; ++f) {
                acc[0][f] = __builtin_amdgcn_mfma_f32_16x16x32_f16(a0, Bf[f][jj], acc[0][f], 0, 0, 0);
                acc[1][f] = __builtin_amdgcn_mfma_f32_16x16x32_f16(a1, Bf[f][jj], acc[1][f], 0, 0, 0);
            }
        }

#pragma unroll
        for (int mt = 0; mt < 2; ++mt)
#pragma unroll
            for (int f = 0; f < 4; ++f)
#pragma unroll
                for (int r = 0; r < 4; ++r)
                    sEpi[half][mt * 16 + q4 + r][wp * 64 + f * 16 + c15] = acc[mt][f][r];
        __syncthreads();

        {
            f16* hdst = hbuf[(t + 1) & 1];
            const float* pbb = pb + n * 256 + jl4 * 4;
            float hvv[4];
            f16x4 hf;
#pragma unroll
            for (int jj = 0; jj < 4; ++jj) {
                f32x4 ga = *(const f32x4*)&sEpi[0][crow][(jl4 + jj) * 4];
                f32x4 gb = *(const f32x4*)&sEpi[1][crow][(jl4 + jj) * 4];
                f32x4 pv = *(const f32x4*)&pbb[jj * 4];
                float vi = ga[0] + gb[0] + pv[0];
                float vf = ga[1] + gb[1] + pv[1];
                float vg = ga[2] + gb[2] + pv[2];
                float vo = ga[3] + gb[3] + pv[3];
                float ig = sigm(vi), fg = sigm(vf), gg = tanh_(vg), og = sigm(vo);
                float cn = fg * cs[jj] + ig * gg;
                float hn = og * tanh_(cn);
                cs[jj] = cn; hvv[jj] = hn; hf[jj] = (f16)hn;
            }
            st64sys(&hdst[(size_t)(b0 + crow) * H_ + n * 64 + jl4],
                    __builtin_bit_cast(u64, hf));
            float4 o = {hvv[0], hvv[1], hvv[2], hvv[3]};
            *(float4*)&out[(size_t)(b0 + crow) * (OUTS * H_) + (size_t)(t + 1) * H_ + n * 64 + jl4] = o;
        }

        if (t + 1 < NSTEP) {
            ++phase;
            asm volatile("s_waitcnt vmcnt(0)" ::: "memory");
            __syncthreads();
            if (tid == 0) {
                __hip_atomic_fetch_add(cnt, 1u, __ATOMIC_RELAXED, __HIP_MEMORY_SCOPE_SYSTEM);
                unsigned spins = 0;
                while (__hip_atomic_load(cnt, __ATOMIC_RELAXED, __HIP_MEMORY_SCOPE_SYSTEM) < phase * 4u) {
                    __builtin_amdgcn_s_sleep(1);
                    if (++spins > (1u << 20)) break;
                }
            }
            __syncthreads();
        }
    }
}

// ---------------------------------------------------------------------------
extern "C" void kernel_launch(void* const* d_in, const int* in_sizes, int n_in,
                              void* d_out, int out_size, void* d_ws, size_t ws_size,
                              hipStream_t stream) {
    const float* x0   = (const float*)d_in[0];
    const float* W_ih = (const float*)d_in[1];
    const float* W_hh = (const float*)d_in[2];
    const float* b_ih = (const float*)d_in[3];
    const float* b_hh = (const float*)d_in[4];
    float* out = (float*)d_out;

    // workspace (~3.6 MB)
    char* p = (char*)d_ws;
    f16* WeP = (f16*)p; p += (size_t)N4H * 512 * 2;
    f16* WaP = (f16*)p; p += (size_t)N4H * 256 * 2;
    float* pb = (float*)p; p += (size_t)N4H * 4;
    f16* hb0 = (f16*)p; p += (size_t)B_ * H_ * 2;
    f16* hb1 = (f16*)p; p += (size_t)B_ * H_ * 2;
    unsigned* cnts = (unsigned*)p; p += (size_t)64 * CNT_STRIDE * 4;

    hipMemsetAsync(hb0, 0, (size_t)B_ * H_ * 2, stream);
    hipMemsetAsync(cnts, 0, (size_t)64 * CNT_STRIDE * 4, stream);

    const int prep_total = N4H * 64 + N4H * 32 + N4H;
    prep_kernel<<<dim3((prep_total + 255) / 256), dim3(256), 0, stream>>>(
        W_ih, W_hh, b_ih, b_hh, WeP, WaP, pb);

    // persistent kernel: 256 blocks (1/CU) x 512 threads (2 waves/SIMD)
    lstm_fused<<<dim3(NBLK), dim3(512), 0, stream>>>(
        x0, WeP, WaP, pb, hb0, hb1, cnts, out);
}